// Round 3
// 1990.746 us; speedup vs baseline: 1.1835x; 1.1835x over previous
//
#include <hip/hip_runtime.h>

// MoE top-2 (DeepSpeed-style) forward on MI355X.
// B=2, S_LEN=2048 -> S=4096 tokens, D=2048, E=8, F=5504, capacity=1024.
// v2c: pre-transpose+convert weights to bf16 [N][K] once (k_wtrans), then both
// GEMMs use the m97 structure: global_load_lds width-16 staging, linear LDS,
// ds_read_b128 fragments, no staging VALU / no scalar LDS writes.
// Tiers by ws_size: 2 = all weights transposed (~665MB), 1 = w1/w3 only (~485MB,
// gemm2 falls back), 0 = previous verified kernels (~191MB).

#define S_TOT 4096
#define DD 2048
#define EE 8
#define FF 5504
#define CAP 1024
#define OUT_MAIN (S_TOT * DD)   // 8388608 floats, then [l_aux][exp_counts x8]

#define BM 128
#define BN 128
#define BK 32
#define BKP 40   // padded row stride for fallback kernels only

typedef __bf16 bf16x8 __attribute__((ext_vector_type(8)));
typedef float f32x4 __attribute__((ext_vector_type(4)));
typedef unsigned int u32;

__device__ __forceinline__ unsigned short f2bf(float f) {
    // round-to-nearest-even fp32 -> bf16 (finite inputs)
    unsigned int u = __builtin_bit_cast(unsigned int, f);
    unsigned int lsb = (u >> 16) & 1u;
    u += 0x7fffu + lsb;
    return (unsigned short)(u >> 16);
}

// async 16B global->LDS (wave-uniform LDS base + lane*16 dest; per-lane global src)
__device__ __forceinline__ void gload16(const void* g, void* l) {
    __builtin_amdgcn_global_load_lds((const __attribute__((address_space(1))) u32*)g,
                                     (__attribute__((address_space(3))) u32*)l, 16, 0, 0);
}

// ---------------- logits = x @ wg  [S,8] ----------------
__global__ void k_logits(const float* __restrict__ x, const float* __restrict__ wg,
                         float* __restrict__ logits) {
    const int s = blockIdx.x;
    const int t = threadIdx.x;  // 256
    const float* xr = x + (size_t)s * DD;
    float part[EE];
#pragma unroll
    for (int e = 0; e < EE; ++e) part[e] = 0.f;
#pragma unroll
    for (int i = 0; i < DD / 256; ++i) {
        int d = t + i * 256;
        float xv = xr[d];
#pragma unroll
        for (int e = 0; e < EE; ++e) part[e] += xv * wg[d * EE + e];
    }
    __shared__ float red[256 * EE];
#pragma unroll
    for (int e = 0; e < EE; ++e) red[t * EE + e] = part[e];
    __syncthreads();
    for (int off = 128; off > 0; off >>= 1) {
        if (t < off) {
#pragma unroll
            for (int e = 0; e < EE; ++e) red[t * EE + e] += red[(t + off) * EE + e];
        }
        __syncthreads();
    }
    if (t < EE) logits[(size_t)s * EE + t] = red[t];
}

// ---------------- top-2 gating, single block, order-preserving scan ----------------
__global__ void k_gating(const float* __restrict__ logits,
                         int* __restrict__ slot1, float* __restrict__ gw1,
                         int* __restrict__ slot2, float* __restrict__ gw2,
                         float* __restrict__ out_extra) {
    const int t = threadIdx.x;  // 256 threads, 16 tokens each (contiguous chunks)
    __shared__ int c1[256][EE];
    __shared__ int c2[256][EE];
    __shared__ float mesh[256][EE];
    __shared__ int tot1[EE];
    __shared__ float me_tot[EE];

    int i1[16], i2[16];
    float g1[16], g2[16];
    int lc1[EE], lc2[EE];
    float lme[EE];
#pragma unroll
    for (int e = 0; e < EE; ++e) { lc1[e] = 0; lc2[e] = 0; lme[e] = 0.f; }

    for (int k = 0; k < 16; ++k) {
        int s = t * 16 + k;
        float lg[EE];
        float m = -1e30f;
#pragma unroll
        for (int e = 0; e < EE; ++e) { lg[e] = logits[(size_t)s * EE + e]; m = fmaxf(m, lg[e]); }
        float ex[EE];
        float sum = 0.f;
#pragma unroll
        for (int e = 0; e < EE; ++e) { ex[e] = expf(lg[e] - m); sum += ex[e]; }
        float inv = 1.f / sum;
        float b1v = -1.f; int b1 = 0;
#pragma unroll
        for (int e = 0; e < EE; ++e) {
            float g = ex[e] * inv;
            lme[e] += g;
            if (g > b1v) { b1v = g; b1 = e; }
        }
        float b2l = -3.4e38f; int b2 = 0;
#pragma unroll
        for (int e = 0; e < EE; ++e) {
            if (e != b1 && lg[e] > b2l) { b2l = lg[e]; b2 = e; }
        }
        float b2v = ex[b2] * inv;
        i1[k] = b1; i2[k] = b2; g1[k] = b1v; g2[k] = b2v;
        lc1[b1]++; lc2[b2]++;
    }
#pragma unroll
    for (int e = 0; e < EE; ++e) { c1[t][e] = lc1[e]; c2[t][e] = lc2[e]; mesh[t][e] = lme[e]; }
    __syncthreads();
    if (t < 8) {
        int run = 0;
        for (int u = 0; u < 256; ++u) { int v = c1[u][t]; c1[u][t] = run; run += v; }
        tot1[t] = run;
    } else if (t < 16) {
        int e = t - 8; int run = 0;
        for (int u = 0; u < 256; ++u) { int v = c2[u][e]; c2[u][e] = run; run += v; }
    } else if (t < 24) {
        int e = t - 16; float sm = 0.f;
        for (int u = 0; u < 256; ++u) sm += mesh[u][e];
        me_tot[e] = sm;
    }
    __syncthreads();
    if (t == 0) {
        float la = 0.f;
        for (int e = 0; e < EE; ++e)
            la += (me_tot[e] / (float)S_TOT) * ((float)tot1[e] / (float)S_TOT);
        la *= (float)EE;
        out_extra[0] = la;
        for (int e = 0; e < EE; ++e) out_extra[1 + e] = (float)tot1[e];
    }
    int o1[EE], o2[EE];
#pragma unroll
    for (int e = 0; e < EE; ++e) { o1[e] = c1[t][e]; o2[e] = c2[t][e]; }
    for (int k = 0; k < 16; ++k) {
        int s = t * 16 + k;
        int e1 = i1[k]; int p1 = o1[e1]++;
        int e2 = i2[k]; int p2 = o2[e2]++ + tot1[e2];
        bool k1 = p1 < CAP, k2 = p2 < CAP;
        float a = k1 ? g1[k] : 0.f;
        float b = k2 ? g2[k] : 0.f;
        float den = fmaxf(a + b, 1e-9f);
        slot1[s] = k1 ? (e1 * CAP + p1) : -1;
        slot2[s] = k2 ? (e2 * CAP + p2) : -1;
        gw1[s] = a / den;
        gw2[s] = b / den;
    }
}

// ---------------- zero xe ----------------
__global__ void k_zero(uint4* __restrict__ p, int n16) {
    int i = blockIdx.x * blockDim.x + threadIdx.x;
    if (i < n16) { uint4 z; z.x = 0; z.y = 0; z.z = 0; z.w = 0; p[i] = z; }
}

// ---------------- scatter tokens into xe bf16 [E,C,D] ----------------
__global__ void k_scatter(const float* __restrict__ x, const int* __restrict__ slot1,
                          const int* __restrict__ slot2, unsigned short* __restrict__ xe) {
    const int s = blockIdx.x >> 1;
    const int sl = (blockIdx.x & 1) ? slot2[s] : slot1[s];
    if (sl < 0) return;
    const float* src = x + (size_t)s * DD;
    unsigned short* dst = xe + (size_t)sl * DD;
    const int d = threadIdx.x * 8;
    float4 u0 = *(const float4*)(src + d);
    float4 u1 = *(const float4*)(src + d + 4);
    union { unsigned short u[8]; uint4 v; } pk;
    pk.u[0] = f2bf(u0.x); pk.u[1] = f2bf(u0.y); pk.u[2] = f2bf(u0.z); pk.u[3] = f2bf(u0.w);
    pk.u[4] = f2bf(u1.x); pk.u[5] = f2bf(u1.y); pk.u[6] = f2bf(u1.z); pk.u[7] = f2bf(u1.w);
    *(uint4*)(dst + d) = pk.v;
}

// ---------------- weight transpose+convert: [R][C] fp32 -> [C][R] bf16 ----------------
// 64x64 tiles; 2x2 register micro-transpose so LDS writes are u32 (2-way conflicts)
// and LDS reads are 4x u32; global reads/writes fully coalesced.
// z+zbase selects matrix: 0..7=w1 expert z&7, 8..15=w3, 16..23=w2.
__global__ __launch_bounds__(256) void k_wtrans(const float* __restrict__ w1,
                                                const float* __restrict__ w3,
                                                const float* __restrict__ w2,
                                                unsigned short* __restrict__ w1t,
                                                unsigned short* __restrict__ w3t,
                                                unsigned short* __restrict__ w2t,
                                                int zbase) {
    const int z = blockIdx.z + zbase;  // matrix(3) x expert(8)
    const int m = z >> 3, e = z & 7;
    const float* src;
    unsigned short* dst;
    int R, C, tx, ty;
    if (m == 0) {
        src = w1 + (size_t)e * DD * FF; dst = w1t + (size_t)e * FF * DD;
        R = DD; C = FF; tx = blockIdx.x; ty = blockIdx.y;           // C/64=86, R/64=32
    } else if (m == 1) {
        src = w3 + (size_t)e * DD * FF; dst = w3t + (size_t)e * FF * DD;
        R = DD; C = FF; tx = blockIdx.x; ty = blockIdx.y;
    } else {
        src = w2 + (size_t)e * FF * DD; dst = w2t + (size_t)e * DD * FF;
        R = FF; C = DD; tx = blockIdx.y; ty = blockIdx.x;           // C/64=32, R/64=86
    }
    if (tx * 64 >= C || ty * 64 >= R) return;
    const int r0 = ty * 64, c0 = tx * 64;
    __shared__ u32 lds[64 * 35];   // [c'][r-pair], pad 35 -> 2-way write conflicts only
    const int t = threadIdx.x;
    const int sc = (t & 31) * 2;       // src col pair
    const int srb = (t >> 5) * 2;      // src row pair base (0..14)
#pragma unroll
    for (int q = 0; q < 4; ++q) {
        const int sr = srb + 16 * q;
        const float* p = src + (size_t)(r0 + sr) * C + c0 + sc;
        float2 a = *(const float2*)p;            // src[r][c], src[r][c+1]
        float2 b = *(const float2*)(p + C);      // src[r+1][c], src[r+1][c+1]
        lds[sc * 35 + (sr >> 1)]       = (u32)f2bf(a.x) | ((u32)f2bf(b.x) << 16);
        lds[(sc + 1) * 35 + (sr >> 1)] = (u32)f2bf(a.y) | ((u32)f2bf(b.y) << 16);
    }
    __syncthreads();
    const int cc = t >> 2, rq = (t & 3) * 4;
    const u32* lp = &lds[cc * 35];
    union { u32 w[4]; uint4 v; } o0, o1;
#pragma unroll
    for (int i = 0; i < 4; ++i) o0.w[i] = lp[rq + i];
#pragma unroll
    for (int i = 0; i < 4; ++i) o1.w[i] = lp[16 + rq + i];
    unsigned short* dp = dst + (size_t)(c0 + cc) * R + r0;
    *(uint4*)(dp + (t & 3) * 8) = o0.v;
    *(uint4*)(dp + 32 + (t & 3) * 8) = o1.v;
}

// ---------------- GEMM1 (m97 structure): h = silu(xe@w1t^T) * (xe@w3t^T) ----------------
// A = xe [C,D] bf16 row-major(K);  B = w1t/w3t [F,D] bf16 row-major(K).
__global__ __launch_bounds__(256, 2) void k_gemm1n(const unsigned short* __restrict__ xe,
                                                   const unsigned short* __restrict__ w1t,
                                                   const unsigned short* __restrict__ w3t,
                                                   unsigned short* __restrict__ h) {
    const int e = blockIdx.z;
    const int cb = blockIdx.x * BM;   // cap dim fastest -> 8 blocks share a B panel
    const int fb = blockIdx.y * BN;
    __shared__ unsigned short As[BM * BK];
    __shared__ unsigned short B1s[BN * BK];
    __shared__ unsigned short B3s[BN * BK];
    const int t = threadIdx.x;
    const int wave = t >> 6, lane = t & 63;
    const int wm = (wave >> 1) * 64, wn = (wave & 1) * 64;
    const int lrow = lane & 15, quad = lane >> 4;
    // staging geometry: lane l of wave w -> LDS ushort idx (base + w*512 + l*8)
    // = row (q*64 + w*16 + l/4), col (l&3)*8 of the 128x32 tile
    const int sr = wave * 16 + (lane >> 2);
    const int sc = (lane & 3) * 8;
    const unsigned short* pa  = xe  + (size_t)e * CAP * DD + (size_t)(cb + sr) * DD + sc;
    const unsigned short* pb1 = w1t + (size_t)e * FF * DD + (size_t)(fb + sr) * DD + sc;
    const unsigned short* pb3 = w3t + (size_t)e * FF * DD + (size_t)(fb + sr) * DD + sc;
    const size_t row64 = (size_t)64 * DD;
    f32x4 acc1[4][4], acc3[4][4];
#pragma unroll
    for (int i = 0; i < 4; ++i)
#pragma unroll
        for (int j = 0; j < 4; ++j) {
            acc1[i][j] = (f32x4){0.f, 0.f, 0.f, 0.f};
            acc3[i][j] = (f32x4){0.f, 0.f, 0.f, 0.f};
        }
    for (int k0 = 0; k0 < DD; k0 += BK) {
        gload16(pa,          &As[wave * 512]);
        gload16(pa + row64,  &As[2048 + wave * 512]);
        gload16(pb1,         &B1s[wave * 512]);
        gload16(pb1 + row64, &B1s[2048 + wave * 512]);
        gload16(pb3,         &B3s[wave * 512]);
        gload16(pb3 + row64, &B3s[2048 + wave * 512]);
        pa += BK; pb1 += BK; pb3 += BK;
        __syncthreads();   // compiler drains vmcnt(0) before barrier
        bf16x8 af[4], b1f[4], b3f[4];
#pragma unroll
        for (int i = 0; i < 4; ++i)
            af[i] = *(const bf16x8*)&As[(wm + i * 16 + lrow) * BK + quad * 8];
#pragma unroll
        for (int j = 0; j < 4; ++j) {
            b1f[j] = *(const bf16x8*)&B1s[(wn + j * 16 + lrow) * BK + quad * 8];
            b3f[j] = *(const bf16x8*)&B3s[(wn + j * 16 + lrow) * BK + quad * 8];
        }
#pragma unroll
        for (int i = 0; i < 4; ++i)
#pragma unroll
            for (int j = 0; j < 4; ++j) {
                acc1[i][j] = __builtin_amdgcn_mfma_f32_16x16x32_bf16(af[i], b1f[j], acc1[i][j], 0, 0, 0);
                acc3[i][j] = __builtin_amdgcn_mfma_f32_16x16x32_bf16(af[i], b3f[j], acc3[i][j], 0, 0, 0);
            }
        __syncthreads();
    }
    unsigned short* H = h + (size_t)e * CAP * FF;
#pragma unroll
    for (int i = 0; i < 4; ++i)
#pragma unroll
        for (int j = 0; j < 4; ++j)
#pragma unroll
            for (int r = 0; r < 4; ++r) {
                float v1 = acc1[i][j][r], v3 = acc3[i][j][r];
                float hv = (v1 / (1.f + __expf(-v1))) * v3;  // silu(v1)*v3
                int row = cb + wm + i * 16 + quad * 4 + r;
                int col = fb + wn + j * 16 + lrow;
                H[(size_t)row * FF + col] = f2bf(hv);
            }
}

// ---------------- GEMM2 (m97 structure): eo = h @ w2t^T, fp32 out ----------------
__global__ __launch_bounds__(256, 2) void k_gemm2n(const unsigned short* __restrict__ h,
                                                   const unsigned short* __restrict__ w2t,
                                                   float* __restrict__ eo) {
    const int e = blockIdx.z;
    const int cb = blockIdx.x * BM;
    const int db = blockIdx.y * BN;
    __shared__ unsigned short As[BM * BK];
    __shared__ unsigned short Bs[BN * BK];
    const int t = threadIdx.x;
    const int wave = t >> 6, lane = t & 63;
    const int wm = (wave >> 1) * 64, wn = (wave & 1) * 64;
    const int lrow = lane & 15, quad = lane >> 4;
    const int sr = wave * 16 + (lane >> 2);
    const int sc = (lane & 3) * 8;
    const unsigned short* pa = h   + (size_t)e * CAP * FF + (size_t)(cb + sr) * FF + sc;
    const unsigned short* pb = w2t + (size_t)e * DD * FF + (size_t)(db + sr) * FF + sc;
    const size_t row64 = (size_t)64 * FF;
    f32x4 acc[4][4];
#pragma unroll
    for (int i = 0; i < 4; ++i)
#pragma unroll
        for (int j = 0; j < 4; ++j) acc[i][j] = (f32x4){0.f, 0.f, 0.f, 0.f};
    for (int k0 = 0; k0 < FF; k0 += BK) {  // 172 iters
        gload16(pa,         &As[wave * 512]);
        gload16(pa + row64, &As[2048 + wave * 512]);
        gload16(pb,         &Bs[wave * 512]);
        gload16(pb + row64, &Bs[2048 + wave * 512]);
        pa += BK; pb += BK;
        __syncthreads();
        bf16x8 af[4], bf[4];
#pragma unroll
        for (int i = 0; i < 4; ++i)
            af[i] = *(const bf16x8*)&As[(wm + i * 16 + lrow) * BK + quad * 8];
#pragma unroll
        for (int j = 0; j < 4; ++j)
            bf[j] = *(const bf16x8*)&Bs[(wn + j * 16 + lrow) * BK + quad * 8];
#pragma unroll
        for (int i = 0; i < 4; ++i)
#pragma unroll
            for (int j = 0; j < 4; ++j)
                acc[i][j] = __builtin_amdgcn_mfma_f32_16x16x32_bf16(af[i], bf[j], acc[i][j], 0, 0, 0);
        __syncthreads();
    }
    float* O = eo + (size_t)e * CAP * DD;
#pragma unroll
    for (int i = 0; i < 4; ++i)
#pragma unroll
        for (int j = 0; j < 4; ++j)
#pragma unroll
            for (int r = 0; r < 4; ++r) {
                int row = cb + wm + i * 16 + quad * 4 + r;
                int col = db + wn + j * 16 + lrow;
                O[(size_t)row * DD + col] = acc[i][j][r];
            }
}

// ---------------- fallback GEMMs (previous verified version, fp32 weights) ----------------
__global__ __launch_bounds__(256, 2) void k_gemm1_fb(const unsigned short* __restrict__ xe,
                                                     const float* __restrict__ w1,
                                                     const float* __restrict__ w3,
                                                     unsigned short* __restrict__ h) {
    const int e = blockIdx.z;
    const int cb = blockIdx.y * BM;
    const int fb = blockIdx.x * BN;
    const unsigned short* A = xe + (size_t)e * CAP * DD;
    const float* W1 = w1 + (size_t)e * DD * FF;
    const float* W3 = w3 + (size_t)e * DD * FF;
    __shared__ unsigned short As[BM * BK];
    __shared__ unsigned short B1s[BN * BKP];
    __shared__ unsigned short B3s[BN * BKP];
    const int t = threadIdx.x;
    const int wave = t >> 6, lane = t & 63;
    const int wm = (wave >> 1) * 64, wn = (wave & 1) * 64;
    const int lrow = lane & 15, quad = lane >> 4;
    f32x4 acc1[4][4], acc3[4][4];
#pragma unroll
    for (int i = 0; i < 4; ++i)
#pragma unroll
        for (int j = 0; j < 4; ++j) {
            acc1[i][j] = (f32x4){0.f, 0.f, 0.f, 0.f};
            acc3[i][j] = (f32x4){0.f, 0.f, 0.f, 0.f};
        }
    const int kk = t >> 3;
    const int ffo = (t & 7) * 16;
    for (int k0 = 0; k0 < DD; k0 += BK) {
#pragma unroll
        for (int i = 0; i < 2; ++i) {
            int idx = t + i * 256;
            int r = idx >> 2, seg = idx & 3;
            *(uint4*)&As[r * BK + seg * 8] =
                *(const uint4*)&A[(size_t)(cb + r) * DD + k0 + seg * 8];
        }
        {
            const float* p1 = &W1[(size_t)(k0 + kk) * FF + fb + ffo];
            const float* p3 = &W3[(size_t)(k0 + kk) * FF + fb + ffo];
            float4 va[4], vc[4];
#pragma unroll
            for (int q = 0; q < 4; ++q) { va[q] = *(const float4*)(p1 + q * 4); }
#pragma unroll
            for (int q = 0; q < 4; ++q) { vc[q] = *(const float4*)(p3 + q * 4); }
            unsigned short* q1 = &B1s[ffo * BKP + kk];
            unsigned short* q3 = &B3s[ffo * BKP + kk];
#pragma unroll
            for (int q = 0; q < 4; ++q) {
                q1[(q * 4 + 0) * BKP] = f2bf(va[q].x);
                q1[(q * 4 + 1) * BKP] = f2bf(va[q].y);
                q1[(q * 4 + 2) * BKP] = f2bf(va[q].z);
                q1[(q * 4 + 3) * BKP] = f2bf(va[q].w);
                q3[(q * 4 + 0) * BKP] = f2bf(vc[q].x);
                q3[(q * 4 + 1) * BKP] = f2bf(vc[q].y);
                q3[(q * 4 + 2) * BKP] = f2bf(vc[q].z);
                q3[(q * 4 + 3) * BKP] = f2bf(vc[q].w);
            }
        }
        __syncthreads();
        bf16x8 af[4], bf1[4], bf3[4];
#pragma unroll
        for (int i = 0; i < 4; ++i)
            af[i] = *(const bf16x8*)&As[(wm + i * 16 + lrow) * BK + quad * 8];
#pragma unroll
        for (int j = 0; j < 4; ++j) {
            bf1[j] = *(const bf16x8*)&B1s[(wn + j * 16 + lrow) * BKP + quad * 8];
            bf3[j] = *(const bf16x8*)&B3s[(wn + j * 16 + lrow) * BKP + quad * 8];
        }
#pragma unroll
        for (int i = 0; i < 4; ++i)
#pragma unroll
            for (int j = 0; j < 4; ++j) {
                acc1[i][j] = __builtin_amdgcn_mfma_f32_16x16x32_bf16(af[i], bf1[j], acc1[i][j], 0, 0, 0);
                acc3[i][j] = __builtin_amdgcn_mfma_f32_16x16x32_bf16(af[i], bf3[j], acc3[i][j], 0, 0, 0);
            }
        __syncthreads();
    }
    unsigned short* H = h + (size_t)e * CAP * FF;
#pragma unroll
    for (int i = 0; i < 4; ++i)
#pragma unroll
        for (int j = 0; j < 4; ++j)
#pragma unroll
            for (int r = 0; r < 4; ++r) {
                float v1 = acc1[i][j][r], v3 = acc3[i][j][r];
                float hv = (v1 / (1.f + __expf(-v1))) * v3;
                int row = cb + wm + i * 16 + quad * 4 + r;
                int col = fb + wn + j * 16 + lrow;
                H[(size_t)row * FF + col] = f2bf(hv);
            }
}

__global__ __launch_bounds__(256, 2) void k_gemm2_fb(const unsigned short* __restrict__ h,
                                                     const float* __restrict__ w2,
                                                     float* __restrict__ eo) {
    const int e = blockIdx.z;
    const int cb = blockIdx.y * BM;
    const int db = blockIdx.x * BN;
    const unsigned short* A = h + (size_t)e * CAP * FF;
    const float* W = w2 + (size_t)e * FF * DD;
    __shared__ unsigned short As[BM * BK];
    __shared__ unsigned short Bs[BN * BKP];
    const int t = threadIdx.x;
    const int wave = t >> 6, lane = t & 63;
    const int wm = (wave >> 1) * 64, wn = (wave & 1) * 64;
    const int lrow = lane & 15, quad = lane >> 4;
    f32x4 acc[4][4];
#pragma unroll
    for (int i = 0; i < 4; ++i)
#pragma unroll
        for (int j = 0; j < 4; ++j) acc[i][j] = (f32x4){0.f, 0.f, 0.f, 0.f};
    const int kk = t >> 3;
    const int ffo = (t & 7) * 16;
    for (int k0 = 0; k0 < FF; k0 += BK) {
#pragma unroll
        for (int i = 0; i < 2; ++i) {
            int idx = t + i * 256;
            int r = idx >> 2, seg = idx & 3;
            *(uint4*)&As[r * BK + seg * 8] =
                *(const uint4*)&A[(size_t)(cb + r) * FF + k0 + seg * 8];
        }
        {
            const float* p = &W[(size_t)(k0 + kk) * DD + db + ffo];
            float4 v[4];
#pragma unroll
            for (int q = 0; q < 4; ++q) v[q] = *(const float4*)(p + q * 4);
            unsigned short* qb = &Bs[ffo * BKP + kk];
#pragma unroll
            for (int q = 0; q < 4; ++q) {
                qb[(q * 4 + 0) * BKP] = f2bf(v[q].x);
                qb[(q * 4 + 1) * BKP] = f2bf(v[q].y);
                qb[(q * 4 + 2) * BKP] = f2bf(v[q].z);
                qb[(q * 4 + 3) * BKP] = f2bf(v[q].w);
            }
        }
        __syncthreads();
        bf16x8 af[4], bf[4];
#pragma unroll
        for (int i = 0; i < 4; ++i)
            af[i] = *(const bf16x8*)&As[(wm + i * 16 + lrow) * BK + quad * 8];
#pragma unroll
        for (int j = 0; j < 4; ++j)
            bf[j] = *(const bf16x8*)&Bs[(wn + j * 16 + lrow) * BKP + quad * 8];
#pragma unroll
        for (int i = 0; i < 4; ++i)
#pragma unroll
            for (int j = 0; j < 4; ++j)
                acc[i][j] = __builtin_amdgcn_mfma_f32_16x16x32_bf16(af[i], bf[j], acc[i][j], 0, 0, 0);
        __syncthreads();
    }
    float* O = eo + (size_t)e * CAP * DD;
#pragma unroll
    for (int i = 0; i < 4; ++i)
#pragma unroll
        for (int j = 0; j < 4; ++j)
#pragma unroll
            for (int r = 0; r < 4; ++r) {
                int row = cb + wm + i * 16 + quad * 4 + r;
                int col = db + wn + j * 16 + lrow;
                O[(size_t)row * DD + col] = acc[i][j][r];
            }
}

// ---------------- combine: out[s] = g1*eo[slot1] + g2*eo[slot2] ----------------
__global__ void k_combine(const float* __restrict__ eo,
                          const int* __restrict__ slot1, const float* __restrict__ gw1,
                          const int* __restrict__ slot2, const float* __restrict__ gw2,
                          float* __restrict__ out) {
    const int s = blockIdx.x, t = threadIdx.x;
    const int sl1 = slot1[s], sl2 = slot2[s];
    const float a = gw1[s], b = gw2[s];
    const int d = t * 8;
    float r[8];
#pragma unroll
    for (int j = 0; j < 8; ++j) r[j] = 0.f;
    if (sl1 >= 0) {
        const float* p = eo + (size_t)sl1 * DD + d;
        float4 u0 = *(const float4*)p, u1 = *(const float4*)(p + 4);
        r[0] += a * u0.x; r[1] += a * u0.y; r[2] += a * u0.z; r[3] += a * u0.w;
        r[4] += a * u1.x; r[5] += a * u1.y; r[6] += a * u1.z; r[7] += a * u1.w;
    }
    if (sl2 >= 0) {
        const float* p = eo + (size_t)sl2 * DD + d;
        float4 u0 = *(const float4*)p, u1 = *(const float4*)(p + 4);
        r[0] += b * u0.x; r[1] += b * u0.y; r[2] += b * u0.z; r[3] += b * u0.w;
        r[4] += b * u1.x; r[5] += b * u1.y; r[6] += b * u1.z; r[7] += b * u1.w;
    }
    float* q = out + (size_t)s * DD + d;
    float4 w0, w1v;
    w0.x = r[0]; w0.y = r[1]; w0.z = r[2]; w0.w = r[3];
    w1v.x = r[4]; w1v.y = r[5]; w1v.z = r[6]; w1v.w = r[7];
    *(float4*)q = w0;
    *(float4*)(q + 4) = w1v;
}

extern "C" void kernel_launch(void* const* d_in, const int* in_sizes, int n_in,
                              void* d_out, int out_size, void* d_ws, size_t ws_size,
                              hipStream_t stream) {
    const float* x  = (const float*)d_in[0];  // [2,2048,2048]
    const float* wg = (const float*)d_in[1];  // [2048,8]
    const float* w1 = (const float*)d_in[2];  // [8,2048,5504]
    const float* w3 = (const float*)d_in[3];  // [8,2048,5504]
    const float* w2 = (const float*)d_in[4];  // [8,5504,2048]
    float* out = (float*)d_out;

    char* ws = (char*)d_ws;
    size_t off = 0;
    float* logits = (float*)(ws + off); off += (size_t)S_TOT * EE * 4;
    int* slot1    = (int*)(ws + off);   off += (size_t)S_TOT * 4;
    float* gw1    = (float*)(ws + off); off += (size_t)S_TOT * 4;
    int* slot2    = (int*)(ws + off);   off += (size_t)S_TOT * 4;
    float* gw2    = (float*)(ws + off); off += (size_t)S_TOT * 4;
    unsigned short* xe   = (unsigned short*)(ws + off); off += (size_t)EE * CAP * DD * 2;   // 33.5 MB
    unsigned short* hbuf = (unsigned short*)(ws + off); off += (size_t)EE * CAP * FF * 2;   // 90.2 MB
    const size_t wmat = (size_t)EE * (size_t)DD * (size_t)FF * 2;   // 180.4 MB each
    // TIER 2 (~665 MB): [w2t][w1t][w3t] after hbuf; eo aliases w1t (dead after gemm1).
    const size_t need_big = off + 3 * wmat;
    unsigned short* w2t_big = (unsigned short*)(ws + off);
    unsigned short* w1t_big = (unsigned short*)(ws + off + wmat);
    unsigned short* w3t_big = (unsigned short*)(ws + off + 2 * wmat);
    float* eo_big = (float*)w1t_big;            // 67.1 MB <= 180.4 MB
    // TIER 1 (~485 MB): [w1t][w3t] after hbuf; gemm2 falls back to fp32 w2;
    // eo aliases w1t (dead after gemm1).
    const size_t need_g1 = off + 2 * wmat;
    unsigned short* w1t_g1 = (unsigned short*)(ws + off);
    unsigned short* w3t_g1 = (unsigned short*)(ws + off + wmat);
    float* eo_g1 = (float*)w1t_g1;
    // TIER 0 (~191 MB): previous verified kernels only.
    float* eo_fb = (float*)(ws + off);

    const int tier = (ws_size >= need_big) ? 2 : (ws_size >= need_g1) ? 1 : 0;

    if (tier == 2)
        k_wtrans<<<dim3(86, 32, 24), 256, 0, stream>>>(w1, w3, w2, w1t_big, w3t_big, w2t_big, 0);
    else if (tier == 1)
        k_wtrans<<<dim3(86, 32, 16), 256, 0, stream>>>(w1, w3, w2, w1t_g1, w3t_g1, nullptr, 0);

    k_logits<<<S_TOT, 256, 0, stream>>>(x, wg, logits);
    k_gating<<<1, 256, 0, stream>>>(logits, slot1, gw1, slot2, gw2, out + OUT_MAIN);
    int n16 = (int)((size_t)EE * CAP * DD * 2 / 16);
    k_zero<<<(n16 + 255) / 256, 256, 0, stream>>>((uint4*)xe, n16);
    k_scatter<<<S_TOT * 2, 256, 0, stream>>>(x, slot1, slot2, xe);

    if (tier == 2) {
        k_gemm1n<<<dim3(CAP / BM, FF / BN, EE), 256, 0, stream>>>(xe, w1t_big, w3t_big, hbuf);
        k_gemm2n<<<dim3(CAP / BM, DD / BN, EE), 256, 0, stream>>>(hbuf, w2t_big, eo_big);
        k_combine<<<S_TOT, 256, 0, stream>>>(eo_big, slot1, gw1, slot2, gw2, out);
    } else if (tier == 1) {
        k_gemm1n<<<dim3(CAP / BM, FF / BN, EE), 256, 0, stream>>>(xe, w1t_g1, w3t_g1, hbuf);
        k_gemm2_fb<<<dim3(DD / BN, CAP / BM, EE), 256, 0, stream>>>(hbuf, w2, eo_g1);
        k_combine<<<S_TOT, 256, 0, stream>>>(eo_g1, slot1, gw1, slot2, gw2, out);
    } else {
        k_gemm1_fb<<<dim3(FF / BN, CAP / BM, EE), 256, 0, stream>>>(xe, w1, w3, hbuf);
        k_gemm2_fb<<<dim3(DD / BN, CAP / BM, EE), 256, 0, stream>>>(hbuf, w2, eo_fb);
        k_combine<<<S_TOT, 256, 0, stream>>>(eo_fb, slot1, gw1, slot2, gw2, out);
    }
}